// Round 9
// baseline (427.527 us; speedup 1.0000x reference)
//
#include <hip/hip_runtime.h>

#define NPTS 16384
#define DH 256
#define PH 4096
#define D2 512

typedef _Float16 f16;
typedef _Float16 f16x4 __attribute__((ext_vector_type(4)));
typedef _Float16 f16x8 __attribute__((ext_vector_type(8)));
typedef float f32x4 __attribute__((ext_vector_type(4)));

// Static device scratch (d_out is only 16 MB = real part; d_ws size unknown).
// All buffers fully rewritten before use each call (deterministic).
// Swizzle convention: within each 64-half (128 B) row chunk, physical 16B
// slot s holds logical slot s^(row&7). Pre-swizzled in GLOBAL layouts so a
// linear global_load_lds produces the swizzled LDS image.
__device__ f16   g_eAtS[(size_t)D2 * NPTS];   // 16 MB: eA^T fp16, swizzled
__device__ f16   g_Tt[2][D2][2*PH];           // 32 MB: T partials [z][d][cs*PH+q]
__device__ f16   g_TsS[(size_t)D2 * 2*PH];    //  8 MB: T summed, [d][2q+cs] swizzled
__device__ float g_G[NPTS][D2];               // 32 MB: G (full-K, no partials)

__device__ __forceinline__ void gload16(const void* g, void* l) {
    __builtin_amdgcn_global_load_lds((const __attribute__((address_space(1))) void*)g,
                                     (__attribute__((address_space(3))) void*)l, 16, 0, 0);
}

__device__ __forceinline__ void fsincos(float x, float* s, float* c) {
    *s = __sinf(x); *c = __cosf(x);
}

// ---------------------------------------------------------------------------
// eA^T precompute, swizzled: g_eAtS[d][64c+8s+i] = eA[64c+8(s^(d&7))+i][d].
// ---------------------------------------------------------------------------
__global__ __launch_bounds__(256) void ker_pre(const float* __restrict__ pts,
                                               const float* __restrict__ A) {
    const int dd = blockIdx.x;           // 0..255
    const int t  = threadIdx.x;          // 64-col chunk c = t
    const float a0 = A[dd], a1 = A[DH + dd], a2 = A[2*DH + dd];
    f16* rowc = &g_eAtS[(size_t)dd*NPTS + t*64];
    f16* rows = &g_eAtS[(size_t)(DH + dd)*NPTS + t*64];
    const int sx = dd & 7;
    #pragma unroll
    for (int s = 0; s < 8; ++s) {
        const int nb = t*64 + 8*(s ^ sx);
        f16x8 vc, vs;
        #pragma unroll
        for (int i = 0; i < 8; ++i) {
            const float* pr = pts + (size_t)(nb + i)*3;
            float sn, cs_; fsincos(pr[0]*a0 + pr[1]*a1 + pr[2]*a2, &sn, &cs_);
            vc[i] = (f16)cs_; vs[i] = (f16)sn;
        }
        *(f16x8*)(rowc + 8*s) = vc;
        *(f16x8*)(rows + 8*s) = vs;
    }
}

// ---------------------------------------------------------------------------
// GEMM1: T = eB^T eA. Producer/consumer: 12 waves = 8 consumers (2Mx4N,
// wave-tile 64x64, MFMA only) + 4 producers (trig ds_write A + gload_lds B).
// Block: M=128 (64 q x {cos,sin}), N=256 d, BK=64 n. Grid (64,2,2)=256=1/CU.
// Consumers compute buf b while producers stage buf b^1 -> MFMA and trig
// pipes overlap between barriers (the 2-barrier lockstep serialized them).
// ---------------------------------------------------------------------------
__global__ __launch_bounds__(768, 3) void ker_T(const float* __restrict__ pts,
                                                const float* __restrict__ B) {
    const int q0 = blockIdx.x * 64;
    const int d0 = blockIdx.y * 256;
    const int ks = blockIdx.z;               // n range [ks*8192, +8192)
    const int t  = threadIdx.x;
    const int lane = t & 63, wid = t >> 6;

    __shared__ f16 Al[2][128][64];   // rows 0..63 cos q, 64..127 sin q (swizzled)
    __shared__ f16 Bl[2][256][64];   // [d][n] (swizzled)

    // consumer maps (wid 0..7)
    const int wm = (wid >> 2) & 1, wn = wid & 3, l7 = lane & 7;
    const int ar = wm*64 + (lane & 15);
    const int br = wn*64 + (lane & 15);
    f32x4 acc[4][4];
    #pragma unroll
    for (int a = 0; a < 4; ++a)
        #pragma unroll
        for (int bq = 0; bq < 4; ++bq) acc[a][bq] = (f32x4){0.f,0.f,0.f,0.f};

    // producer maps (wid 8..11); pt/qq valid-but-unused for consumers
    const int pid = wid & 3;
    const int pt  = t & 255;
    const int qq  = pt >> 2;                 // q-row 0..63
    const int nch = (pt & 3) * 16;           // 16 n per lane
    const int s0  = (pt & 3) * 2;            // logical slot base
    const int sx  = qq & 7;
    const float b0 = B[q0+qq], b1 = B[PH+q0+qq], b2 = B[2*PH+q0+qq];
    const size_t bsrc0 = (size_t)(d0 + 64*pid + (lane >> 3))*NPTS + 8*(lane & 7);

#define STAGE_T(bb, nb_) do {                                                  \
    _Pragma("unroll")                                                          \
    for (int i = 0; i < 8; ++i)                                                \
        gload16(&g_eAtS[0] + bsrc0 + (size_t)(8*i)*NPTS + (size_t)(nb_),       \
                &Bl[bb][64*pid + 8*i][0]);                                     \
    const float* pb = pts + (size_t)((nb_) + nch)*3;                           \
    f16x8 vc0, vc1, vs0, vs1;                                                  \
    _Pragma("unroll")                                                          \
    for (int g = 0; g < 4; ++g) {                                              \
        const float4 Pa = *(const float4*)(pb + 12*g);                         \
        const float4 Pb = *(const float4*)(pb + 12*g + 4);                     \
        const float4 Pc = *(const float4*)(pb + 12*g + 8);                     \
        const float xx[4] = {Pa.x, Pa.w, Pb.z, Pc.y};                          \
        const float yy[4] = {Pa.y, Pb.x, Pb.w, Pc.z};                          \
        const float zz[4] = {Pa.z, Pb.y, Pc.x, Pc.w};                          \
        _Pragma("unroll")                                                      \
        for (int u = 0; u < 4; ++u) {                                          \
            float sn, cc; fsincos(xx[u]*b0 + yy[u]*b1 + zz[u]*b2, &sn, &cc);   \
            const int idx = 4*g + u;                                           \
            if (idx < 8) { vc0[idx] = (f16)cc; vs0[idx] = (f16)sn; }           \
            else         { vc1[idx-8] = (f16)cc; vs1[idx-8] = (f16)sn; }       \
        }                                                                      \
    }                                                                          \
    *(f16x8*)&Al[bb][qq][((s0  ) ^ sx)*8]      = vc0;                          \
    *(f16x8*)&Al[bb][qq][((s0+1) ^ sx)*8]      = vc1;                          \
    *(f16x8*)&Al[bb][64 + qq][((s0  ) ^ sx)*8] = vs0;                          \
    *(f16x8*)&Al[bb][64 + qq][((s0+1) ^ sx)*8] = vs1;                          \
} while (0)

    if (wid >= 8) STAGE_T(0, ks*8192);
    __syncthreads();

    #pragma unroll 2
    for (int tt = 0; tt < 128; ++tt) {
        const int b = tt & 1;
        if (wid < 8) {
            #pragma unroll
            for (int kk = 0; kk < 2; ++kk) {
                f16x8 af[4], bf[4];
                #pragma unroll
                for (int mf = 0; mf < 4; ++mf)
                    af[mf] = *(const f16x8*)&Al[b][ar + mf*16][(((lane>>4) + 4*kk) ^ l7)*8];
                #pragma unroll
                for (int nf = 0; nf < 4; ++nf)
                    bf[nf] = *(const f16x8*)&Bl[b][br + nf*16][(((lane>>4) + 4*kk) ^ l7)*8];
                #pragma unroll
                for (int mf = 0; mf < 4; ++mf)
                    #pragma unroll
                    for (int nf = 0; nf < 4; ++nf)
                        acc[mf][nf] = __builtin_amdgcn_mfma_f32_16x16x32_f16(
                            af[mf], bf[nf], acc[mf][nf], 0, 0, 0);
            }
        } else if (tt < 127) {
            STAGE_T(b^1, ks*8192 + (tt+1)*64);
        }
        __syncthreads();
    }
#undef STAGE_T

    if (wid < 8) {
        // wave wm=0 -> cos rows, wm=1 -> sin rows; D row=(l>>4)*4+j, col=l&15
        #pragma unroll
        for (int mf = 0; mf < 4; ++mf) {
            const int qrow = q0 + mf*16 + (lane >> 4)*4;
            #pragma unroll
            for (int nf = 0; nf < 4; ++nf) {
                const int d = d0 + wn*64 + nf*16 + (lane & 15);
                f16x4 v;
                #pragma unroll
                for (int j = 0; j < 4; ++j) v[j] = (f16)acc[mf][nf][j];
                *(f16x4*)&g_Tt[ks][d][(size_t)wm*PH + qrow] = v;
            }
        }
    }
}

// ---------------------------------------------------------------------------
// Sum 2 T partials -> g_TsS, interleaved [d][2q+cs], swizzled per 64-chunk.
// ---------------------------------------------------------------------------
__global__ __launch_bounds__(256) void ker_tsum() {
    const int u  = blockIdx.x*256 + threadIdx.x;   // 2048 blocks
    const int d  = u >> 10;
    const int jj = u & 1023;
    const int c = jj >> 3, s = jj & 7;
    const int klb = 64*c + 8*(s ^ (d & 7));        // logical interleaved-k base
    const int q0_ = klb >> 1;
    float oc[4] = {0,0,0,0}, os[4] = {0,0,0,0};
    #pragma unroll
    for (int z = 0; z < 2; ++z) {
        const f16x4 a  = *(const f16x4*)&g_Tt[z][d][q0_];
        const f16x4 bs = *(const f16x4*)&g_Tt[z][d][PH + q0_];
        #pragma unroll
        for (int j = 0; j < 4; ++j) { oc[j] += (float)a[j]; os[j] += (float)bs[j]; }
    }
    f16x8 v;
    #pragma unroll
    for (int j = 0; j < 4; ++j) { v[2*j] = (f16)oc[j]; v[2*j+1] = (f16)os[j]; }
    *(f16x8*)&g_TsS[(size_t)d*(2*PH) + 64*c + 8*s] = v;
}

// ---------------------------------------------------------------------------
// GEMM2: G = eB T. Same producer/consumer structure. Block: M=128 n, N=256 d,
// BK=64 interleaved k (=32 q x {cos,sin}). Grid (128,2,1) = 256 = 1/CU.
// ---------------------------------------------------------------------------
__global__ __launch_bounds__(768, 3) void ker_G(const float* __restrict__ pts,
                                                const float* __restrict__ B) {
    const int n0 = blockIdx.x * 128;
    const int d0 = blockIdx.y * 256;
    const int t  = threadIdx.x;
    const int lane = t & 63, wid = t >> 6;

    __shared__ f16 Al[2][128][64];   // [n][ik] swizzled
    __shared__ f16 Bl[2][256][64];   // [d][ik] swizzled

    const int wm = (wid >> 2) & 1, wn = wid & 3, l7 = lane & 7;
    const int ar = wm*64 + (lane & 15);
    const int br = wn*64 + (lane & 15);
    f32x4 acc[4][4];
    #pragma unroll
    for (int a = 0; a < 4; ++a)
        #pragma unroll
        for (int bq = 0; bq < 4; ++bq) acc[a][bq] = (f32x4){0.f,0.f,0.f,0.f};

    // producer maps
    const int pid   = wid & 3;
    const int pt    = t & 255;
    const int nn    = pt >> 1;               // n-row 0..127
    const int qch   = (pt & 1) * 16;         // 16 q per lane
    const int sbase = (pt & 1) * 4;
    const int sx    = nn & 7;
    const float px = pts[(size_t)(n0+nn)*3];
    const float py = pts[(size_t)(n0+nn)*3 + 1];
    const float pz = pts[(size_t)(n0+nn)*3 + 2];
    const size_t bsrc0 = (size_t)(d0 + 64*pid + (lane >> 3))*(2*PH) + 8*(lane & 7);

#define STAGE_G(bb, tile_) do {                                                \
    const int kb = (tile_)*64;                                                 \
    _Pragma("unroll")                                                          \
    for (int i = 0; i < 8; ++i)                                                \
        gload16(&g_TsS[0] + bsrc0 + (size_t)(8*i)*(2*PH) + (size_t)kb,         \
                &Bl[bb][64*pid + 8*i][0]);                                     \
    const int qg = (tile_)*32 + qch;                                           \
    _Pragma("unroll")                                                          \
    for (int g = 0; g < 4; ++g) {                                              \
        const float4 X = *(const float4*)&B[qg + 4*g];                         \
        const float4 Y = *(const float4*)&B[PH + qg + 4*g];                    \
        const float4 Z = *(const float4*)&B[2*PH + qg + 4*g];                  \
        f16x8 vv;                                                              \
        { float sn, cc; fsincos(px*X.x + py*Y.x + pz*Z.x, &sn, &cc); vv[0]=(f16)cc; vv[1]=(f16)sn; } \
        { float sn, cc; fsincos(px*X.y + py*Y.y + pz*Z.y, &sn, &cc); vv[2]=(f16)cc; vv[3]=(f16)sn; } \
        { float sn, cc; fsincos(px*X.z + py*Y.z + pz*Z.z, &sn, &cc); vv[4]=(f16)cc; vv[5]=(f16)sn; } \
        { float sn, cc; fsincos(px*X.w + py*Y.w + pz*Z.w, &sn, &cc); vv[6]=(f16)cc; vv[7]=(f16)sn; } \
        *(f16x8*)&Al[bb][nn][((sbase + g) ^ sx)*8] = vv;                       \
    }                                                                          \
} while (0)

    if (wid >= 8) STAGE_G(0, 0);
    __syncthreads();

    #pragma unroll 2
    for (int tt = 0; tt < 128; ++tt) {
        const int b = tt & 1;
        if (wid < 8) {
            #pragma unroll
            for (int kk = 0; kk < 2; ++kk) {
                f16x8 af[4], bf[4];
                #pragma unroll
                for (int mf = 0; mf < 4; ++mf)
                    af[mf] = *(const f16x8*)&Al[b][ar + mf*16][(((lane>>4) + 4*kk) ^ l7)*8];
                #pragma unroll
                for (int nf = 0; nf < 4; ++nf)
                    bf[nf] = *(const f16x8*)&Bl[b][br + nf*16][(((lane>>4) + 4*kk) ^ l7)*8];
                #pragma unroll
                for (int mf = 0; mf < 4; ++mf)
                    #pragma unroll
                    for (int nf = 0; nf < 4; ++nf)
                        acc[mf][nf] = __builtin_amdgcn_mfma_f32_16x16x32_f16(
                            af[mf], bf[nf], acc[mf][nf], 0, 0, 0);
            }
        } else if (tt < 127) {
            STAGE_G(b^1, tt + 1);
        }
        __syncthreads();
    }
#undef STAGE_G

    if (wid < 8) {
        #pragma unroll
        for (int mf = 0; mf < 4; ++mf) {
            const int nbase = n0 + wm*64 + mf*16 + (lane >> 4)*4;
            #pragma unroll
            for (int nf = 0; nf < 4; ++nf) {
                const int d = d0 + wn*64 + nf*16 + (lane & 15);
                #pragma unroll
                for (int j = 0; j < 4; ++j)
                    g_G[nbase + j][d] = acc[mf][nf][j];
            }
        }
    }
}

// ---------------------------------------------------------------------------
// Epilogue: Gc = (Gr+i*Gi)*conj(e^{i alpha}) (|e^{ia}|=1, divide==conj-mult;
// rotation preserves row norm -> scale = 16/||G row||). Output = REAL part.
// ---------------------------------------------------------------------------
__global__ __launch_bounds__(256) void ker_fin(const float* __restrict__ pts,
                                               const float* __restrict__ A,
                                               float* __restrict__ out) {
    const int n = blockIdx.x;
    const int k = threadIdx.x;  // 0..255
    const float p0 = pts[(size_t)n*3], p1 = pts[(size_t)n*3+1], p2 = pts[(size_t)n*3+2];
    const float alp = p0*A[k] + p1*A[DH + k] + p2*A[2*DH + k];
    float sa, ca; fsincos(alp, &sa, &ca);
    const float Gr = g_G[n][k];
    const float Gi = g_G[n][DH + k];
    const float Re = Gr*ca + Gi*sa;
    float nr = Gr*Gr + Gi*Gi;
    #pragma unroll
    for (int off = 32; off > 0; off >>= 1) nr += __shfl_down(nr, off, 64);
    __shared__ float wsum[4];
    if ((k & 63) == 0) wsum[k >> 6] = nr;
    __syncthreads();
    const float total = wsum[0] + wsum[1] + wsum[2] + wsum[3];
    const float scale = 16.0f * rsqrtf(total);
    out[(size_t)n*DH + k] = Re * scale;
}

extern "C" void kernel_launch(void* const* d_in, const int* in_sizes, int n_in,
                              void* d_out, int out_size, void* d_ws, size_t ws_size,
                              hipStream_t stream) {
    const float* pts = (const float*)d_in[0];
    const float* A   = (const float*)d_in[1];
    const float* B   = (const float*)d_in[2];
    float* out = (float*)d_out;
    (void)d_ws; (void)ws_size; (void)out_size;

    ker_pre <<<256, 256, 0, stream>>>(pts, A);
    ker_T   <<<dim3(64, 2, 2), 768, 0, stream>>>(pts, B);
    ker_tsum<<<2048, 256, 0, stream>>>();
    ker_G   <<<dim3(128, 2, 1), 768, 0, stream>>>(pts, B);
    ker_fin <<<16384, 256, 0, stream>>>(pts, A, out);
}

// Round 10
// 368.995 us; speedup vs baseline: 1.1586x; 1.1586x over previous
//
#include <hip/hip_runtime.h>

#define NPTS 16384
#define DH 256
#define PH 4096
#define D2 512
#define LDA 40   // ker_G A-tile pad (R8 value)
#define LDT 72   // ker_T A-tile pad (BK=64 + 8)

typedef _Float16 f16;
typedef _Float16 f16x4 __attribute__((ext_vector_type(4)));
typedef _Float16 f16x8 __attribute__((ext_vector_type(8)));
typedef float f32x4 __attribute__((ext_vector_type(4)));

// Static device scratch (d_out is only 16 MB = real part; d_ws size unknown).
// All buffers fully rewritten before use each call (deterministic).
// g_eAtS swizzle: within each 64-half (128 B) row chunk, physical 16B slot s
// holds logical slot s^(d&7) -> linear global_load_lds yields swizzled LDS.
__device__ f16   g_eAtS[(size_t)D2 * NPTS];   // 16 MB: eA^T fp16, swizzled
__device__ f16   g_Tt[4][D2][2*PH];           // 64 MB: T K-split partials
__device__ f16   g_Ts[D2][2*PH];              //  8 MB: summed T^T, linear
__device__ float g_G[2][NPTS][D2];            // 64 MB: G K-split partials

__device__ __forceinline__ void gload16(const void* g, void* l) {
    __builtin_amdgcn_global_load_lds((const __attribute__((address_space(1))) void*)g,
                                     (__attribute__((address_space(3))) void*)l, 16, 0, 0);
}

__device__ __forceinline__ void fsincos(float x, float* s, float* c) {
    *s = __sinf(x); *c = __cosf(x);
}

// ---------------------------------------------------------------------------
// eA^T precompute, swizzled: g_eAtS[d][64c+8s+i] = eA[64c+8(s^(d&7))+i][d].
// ---------------------------------------------------------------------------
__global__ __launch_bounds__(256) void ker_pre(const float* __restrict__ pts,
                                               const float* __restrict__ A) {
    const int dd = blockIdx.x;           // 0..255
    const int t  = threadIdx.x;          // 64-col chunk c = t
    const float a0 = A[dd], a1 = A[DH + dd], a2 = A[2*DH + dd];
    f16* rowc = &g_eAtS[(size_t)dd*NPTS + t*64];
    f16* rows = &g_eAtS[(size_t)(DH + dd)*NPTS + t*64];
    const int sx = dd & 7;
    #pragma unroll
    for (int s = 0; s < 8; ++s) {
        const int nb = t*64 + 8*(s ^ sx);
        f16x8 vc, vs;
        #pragma unroll
        for (int i = 0; i < 8; ++i) {
            const float* pr = pts + (size_t)(nb + i)*3;
            float sn, cs_; fsincos(pr[0]*a0 + pr[1]*a1 + pr[2]*a2, &sn, &cs_);
            vc[i] = (f16)cs_; vs[i] = (f16)sn;
        }
        *(f16x8*)(rowc + 8*s) = vc;
        *(f16x8*)(rows + 8*s) = vs;
    }
}

// ---------------------------------------------------------------------------
// GEMM1: T = eB^T eA. Block: M=128 (64 q x {cos,sin}), N=256 d, BK=64 n
// (vs R8's BK=32: halves barrier count -- ker_T's only deficit vs ker_G).
// Grid (64,2,4) = 1024 blocks. 512 thr, 8 waves (2M x 4N), wave-tile 64x64.
// A (eB) trig -> padded ds_write; B (eA^T) swizzled global_load_lds.
// ---------------------------------------------------------------------------
__global__ __launch_bounds__(512) void ker_T(const float* __restrict__ pts,
                                             const float* __restrict__ B) {
    const int q0 = blockIdx.x * 64;
    const int d0 = blockIdx.y * 256;
    const int ks = blockIdx.z;               // n range [ks*4096, +4096)
    const int t  = threadIdx.x;
    const int lane = t & 63, wid = t >> 6;
    const int wm = wid >> 2, wn = wid & 3;
    const int l7 = lane & 7;

    __shared__ f16 Al[128][LDT];   // rows 0..63 cos q, 64..127 sin q (padded)
    __shared__ f16 Bl[256][64];    // [d][n] swizzled (gload_lds dest)

    f32x4 acc[4][4];
    #pragma unroll
    for (int a = 0; a < 4; ++a)
        #pragma unroll
        for (int bq = 0; bq < 4; ++bq) acc[a][bq] = (f32x4){0.f,0.f,0.f,0.f};

    // A-trig: qq = t>>3 (0..63), 8 n per iter at nn0=(t&7)*8
    const int qq  = t >> 3;
    const int nn0 = (t & 7) * 8;
    const float b0 = B[q0+qq], b1 = B[PH+q0+qq], b2 = B[2*PH+q0+qq];
    // B gload: wave covers rows 32*wid..+31 in 4 gloads of 8 rows each
    const size_t bsrc0 = (size_t)(d0 + 32*wid + (lane >> 3))*NPTS + 8*l7;
    // frag coords
    const int mrow = wm*64 + (lane & 15);
    const int ncol = wn*64 + (lane & 15);

    for (int c = 0; c < 64; ++c) {
        const int nb = ks*4096 + c*64;
        __syncthreads();   // previous compute's LDS reads done
        // B stage first (HBM latency hides under trig)
        #pragma unroll
        for (int i = 0; i < 4; ++i)
            gload16(&g_eAtS[0] + bsrc0 + (size_t)(8*i)*NPTS + (size_t)nb,
                    &Bl[32*wid + 8*i][0]);
        {   // A stage: 8 consecutive pts rows = 24 contiguous floats
            const float* pb = pts + (size_t)(nb + nn0)*3;
            const float4 F0 = *(const float4*)(pb);
            const float4 F1 = *(const float4*)(pb + 4);
            const float4 F2 = *(const float4*)(pb + 8);
            const float4 F3 = *(const float4*)(pb + 12);
            const float4 F4 = *(const float4*)(pb + 16);
            const float4 F5 = *(const float4*)(pb + 20);
            const float xx[8] = {F0.x, F0.w, F1.z, F2.y, F3.x, F3.w, F4.z, F5.y};
            const float yy[8] = {F0.y, F1.x, F1.w, F2.z, F3.y, F4.x, F4.w, F5.z};
            const float zz[8] = {F0.z, F1.y, F2.x, F2.w, F3.z, F4.y, F5.x, F5.w};
            f16x8 vc, vs;
            #pragma unroll
            for (int u = 0; u < 8; ++u) {
                float sn, cc; fsincos(xx[u]*b0 + yy[u]*b1 + zz[u]*b2, &sn, &cc);
                vc[u] = (f16)cc; vs[u] = (f16)sn;
            }
            *(f16x8*)&Al[qq][nn0]      = vc;
            *(f16x8*)&Al[64 + qq][nn0] = vs;
        }
        __syncthreads();   // drains vmcnt+lgkmcnt (compiler-emitted)
        #pragma unroll
        for (int kk = 0; kk < 2; ++kk) {
            f16x8 af[4], bf[4];
            #pragma unroll
            for (int mf = 0; mf < 4; ++mf)
                af[mf] = *(const f16x8*)&Al[mrow + mf*16][32*kk + (lane >> 4)*8];
            #pragma unroll
            for (int nf = 0; nf < 4; ++nf)
                bf[nf] = *(const f16x8*)&Bl[ncol + nf*16][(((lane >> 4) + 4*kk) ^ l7)*8];
            #pragma unroll
            for (int mf = 0; mf < 4; ++mf)
                #pragma unroll
                for (int nf = 0; nf < 4; ++nf)
                    acc[mf][nf] = __builtin_amdgcn_mfma_f32_16x16x32_f16(
                        af[mf], bf[nf], acc[mf][nf], 0, 0, 0);
        }
    }
    // epilogue: wave wm: 0=cos rows, 1=sin rows; D row=(l>>4)*4+j, col=l&15
    #pragma unroll
    for (int mf = 0; mf < 4; ++mf) {
        const int qrow = q0 + mf*16 + (lane >> 4)*4;
        #pragma unroll
        for (int nf = 0; nf < 4; ++nf) {
            const int d = d0 + wn*64 + nf*16 + (lane & 15);
            f16x4 v;
            #pragma unroll
            for (int j = 0; j < 4; ++j) v[j] = (f16)acc[mf][nf][j];
            *(f16x4*)&g_Tt[ks][d][(size_t)wm*PH + qrow] = v;
        }
    }
}

// ---------------------------------------------------------------------------
// Sum 4 T partials -> g_Ts fp16 (linear).
// ---------------------------------------------------------------------------
__global__ __launch_bounds__(256) void ker_tsum() {
    const size_t i = ((size_t)blockIdx.x*256 + threadIdx.x) * 8;
    float o[8] = {0,0,0,0,0,0,0,0};
    #pragma unroll
    for (int z = 0; z < 4; ++z) {
        const f16x8 v = *(const f16x8*)(&g_Tt[z][0][0] + i);
        #pragma unroll
        for (int j = 0; j < 8; ++j) o[j] += (float)v[j];
    }
    f16x8 r;
    #pragma unroll
    for (int j = 0; j < 8; ++j) r[j] = (f16)o[j];
    *(f16x8*)(&g_Ts[0][0] + i) = r;
}

// ---------------------------------------------------------------------------
// GEMM2: G = eB T. Block: M=128 n, N=256 d, 32 q per iter (K eff 64).
// Grid (128, 2, 2) = 512 blocks. 512 thr, 8 waves (2M x 4N), wave-tile 64x64.
// A (eB cos/sin) trig->ds_write; B (Ts cos/sin cols) global_load_lds. [R8]
// ---------------------------------------------------------------------------
__global__ __launch_bounds__(512) void ker_G(const float* __restrict__ pts,
                                             const float* __restrict__ B) {
    const int n0 = blockIdx.x * 128;
    const int d0 = blockIdx.y * 256;
    const int ks = blockIdx.z;               // q range [ks*2048, +2048)
    const int t  = threadIdx.x;
    const int lane = t & 63, wid = t >> 6;
    const int wm = wid >> 2, wn = wid & 3;

    __shared__ f16 Ac[128][LDA], As[128][LDA];   // eB cos/sin [n][q] padded
    __shared__ f16 Bc[256][32],  Bs[256][32];    // Ts cols    [d][q] linear

    f32x4 acc[4][4];
    #pragma unroll
    for (int a = 0; a < 4; ++a)
        #pragma unroll
        for (int bq = 0; bq < 4; ++bq) acc[a][bq] = (f32x4){0.f,0.f,0.f,0.f};

    // A-trig: nn = t>>2 (0..127) fixed pts row; 8 q per iter at qq0=(t&3)*8
    const int nn  = t >> 2;
    const int qq0 = (t & 3) * 8;
    const float px = pts[(size_t)(n0+nn)*3];
    const float py = pts[(size_t)(n0+nn)*3 + 1];
    const float pz = pts[(size_t)(n0+nn)*3 + 2];
    // B gload
    const size_t bsrc0 = (size_t)(d0 + 32*wid + (lane >> 2))*(2*PH) + 8*(lane & 3);
    const int mrow = wm*64 + (lane & 15);
    const int ncol = wn*64 + (lane & 15);
    const int kof  = (lane >> 4) * 8;

    for (int c = 0; c < 64; ++c) {
        const int qk = ks*2048 + c*32;
        __syncthreads();
        // B stage: 4 x gload16 (cos rows x2, sin rows x2)
        gload16(&g_Ts[0][0] + bsrc0 + (size_t)qk,                            &Bc[32*wid][0]);
        gload16(&g_Ts[0][0] + bsrc0 + (size_t)16*(2*PH) + (size_t)qk,        &Bc[32*wid + 16][0]);
        gload16(&g_Ts[0][0] + bsrc0 + (size_t)PH + (size_t)qk,               &Bs[32*wid][0]);
        gload16(&g_Ts[0][0] + bsrc0 + (size_t)(16*(2*PH) + PH) + (size_t)qk, &Bs[32*wid + 16][0]);
        {   // A stage: 8 betas for fixed n-row
            const int qg = qk + qq0;
            const float4 bx0 = *(const float4*)&B[qg];
            const float4 bx1 = *(const float4*)&B[qg + 4];
            const float4 by0 = *(const float4*)&B[PH + qg];
            const float4 by1 = *(const float4*)&B[PH + qg + 4];
            const float4 bz0 = *(const float4*)&B[2*PH + qg];
            const float4 bz1 = *(const float4*)&B[2*PH + qg + 4];
            const float bx[8] = {bx0.x,bx0.y,bx0.z,bx0.w, bx1.x,bx1.y,bx1.z,bx1.w};
            const float by[8] = {by0.x,by0.y,by0.z,by0.w, by1.x,by1.y,by1.z,by1.w};
            const float bz[8] = {bz0.x,bz0.y,bz0.z,bz0.w, bz1.x,bz1.y,bz1.z,bz1.w};
            f16x8 vc, vs;
            #pragma unroll
            for (int u = 0; u < 8; ++u) {
                float sn, cc; fsincos(px*bx[u] + py*by[u] + pz*bz[u], &sn, &cc);
                vc[u] = (f16)cc; vs[u] = (f16)sn;
            }
            *(f16x8*)&Ac[nn][qq0] = vc;
            *(f16x8*)&As[nn][qq0] = vs;
        }
        __syncthreads();
        f16x8 a1[4], a2[4], b1[4], b2[4];
        #pragma unroll
        for (int mf = 0; mf < 4; ++mf) {
            a1[mf] = *(const f16x8*)&Ac[mrow + mf*16][kof];
            a2[mf] = *(const f16x8*)&As[mrow + mf*16][kof];
        }
        #pragma unroll
        for (int nf = 0; nf < 4; ++nf) {
            b1[nf] = *(const f16x8*)&Bc[ncol + nf*16][kof];
            b2[nf] = *(const f16x8*)&Bs[ncol + nf*16][kof];
        }
        #pragma unroll
        for (int mf = 0; mf < 4; ++mf)
            #pragma unroll
            for (int nf = 0; nf < 4; ++nf) {
                acc[mf][nf] = __builtin_amdgcn_mfma_f32_16x16x32_f16(
                    a1[mf], b1[nf], acc[mf][nf], 0, 0, 0);
                acc[mf][nf] = __builtin_amdgcn_mfma_f32_16x16x32_f16(
                    a2[mf], b2[nf], acc[mf][nf], 0, 0, 0);
            }
    }
    // epilogue -> g_G[ks][n][d] fp32
    #pragma unroll
    for (int mf = 0; mf < 4; ++mf) {
        const int nbase = n0 + wm*64 + mf*16 + (lane >> 4)*4;
        #pragma unroll
        for (int nf = 0; nf < 4; ++nf) {
            const int d = d0 + wn*64 + nf*16 + (lane & 15);
            #pragma unroll
            for (int j = 0; j < 4; ++j)
                g_G[ks][nbase + j][d] = acc[mf][nf][j];
        }
    }
}

// ---------------------------------------------------------------------------
// Epilogue: Gc = (Gr+i*Gi)*conj(e^{i alpha}) (|e^{ia}|=1, divide==conj-mult;
// rotation preserves row norm -> scale = 16/||G row||). Output = REAL part.
// ---------------------------------------------------------------------------
__global__ __launch_bounds__(256) void ker_fin(const float* __restrict__ pts,
                                               const float* __restrict__ A,
                                               float* __restrict__ out) {
    const int n = blockIdx.x;
    const int k = threadIdx.x;  // 0..255
    const float p0 = pts[(size_t)n*3], p1 = pts[(size_t)n*3+1], p2 = pts[(size_t)n*3+2];
    const float alp = p0*A[k] + p1*A[DH + k] + p2*A[2*DH + k];
    float sa, ca; fsincos(alp, &sa, &ca);
    const float Gr = g_G[0][n][k]      + g_G[1][n][k];
    const float Gi = g_G[0][n][DH + k] + g_G[1][n][DH + k];
    const float Re = Gr*ca + Gi*sa;
    float nr = Gr*Gr + Gi*Gi;
    #pragma unroll
    for (int off = 32; off > 0; off >>= 1) nr += __shfl_down(nr, off, 64);
    __shared__ float wsum[4];
    if ((k & 63) == 0) wsum[k >> 6] = nr;
    __syncthreads();
    const float total = wsum[0] + wsum[1] + wsum[2] + wsum[3];
    const float scale = 16.0f * rsqrtf(total);
    out[(size_t)n*DH + k] = Re * scale;
}

extern "C" void kernel_launch(void* const* d_in, const int* in_sizes, int n_in,
                              void* d_out, int out_size, void* d_ws, size_t ws_size,
                              hipStream_t stream) {
    const float* pts = (const float*)d_in[0];
    const float* A   = (const float*)d_in[1];
    const float* B   = (const float*)d_in[2];
    float* out = (float*)d_out;
    (void)d_ws; (void)ws_size; (void)out_size;

    ker_pre <<<256, 256, 0, stream>>>(pts, A);
    ker_T   <<<dim3(64, 2, 4), 512, 0, stream>>>(pts, B);
    ker_tsum<<<2048, 256, 0, stream>>>();
    ker_G   <<<dim3(128, 2, 2), 512, 0, stream>>>(pts, B);
    ker_fin <<<16384, 256, 0, stream>>>(pts, A, out);
}

// Round 11
// 359.185 us; speedup vs baseline: 1.1903x; 1.0273x over previous
//
#include <hip/hip_runtime.h>

#define NPTS 16384
#define DH 256
#define PH 4096
#define D2 512
#define LDT 72   // padded A-tile K-stride (BK=64 + 8): 144B rows -> 2-way banks (free)

typedef _Float16 f16;
typedef _Float16 f16x4 __attribute__((ext_vector_type(4)));
typedef _Float16 f16x8 __attribute__((ext_vector_type(8)));
typedef float f32x4 __attribute__((ext_vector_type(4)));

// Static device scratch (d_out is only 16 MB = real part; d_ws size unknown).
// All buffers fully rewritten before use each call (deterministic).
// Swizzle convention (B-side tiles): within each 64-half (128 B) row chunk,
// physical 16B slot s holds logical slot s^(row&7). Pre-swizzled in GLOBAL
// layouts so linear global_load_lds yields the swizzled LDS image.
__device__ f16   g_eAtS[(size_t)D2 * NPTS];   // 16 MB: eA^T fp16, swizzled
__device__ f16   g_Tt[4][D2][2*PH];           // 64 MB: T K-split partials [z][d][cs*PH+q]
__device__ f16   g_TsS[(size_t)D2 * 2*PH];    //  8 MB: T summed, [d][2q+cs] swizzled
__device__ float g_G[2][NPTS][D2];            // 64 MB: G K-split partials

__device__ __forceinline__ void gload16(const void* g, void* l) {
    __builtin_amdgcn_global_load_lds((const __attribute__((address_space(1))) void*)g,
                                     (__attribute__((address_space(3))) void*)l, 16, 0, 0);
}

__device__ __forceinline__ void fsincos(float x, float* s, float* c) {
    *s = __sinf(x); *c = __cosf(x);
}

// ---------------------------------------------------------------------------
// eA^T precompute, swizzled: g_eAtS[d][64c+8s+i] = eA[64c+8(s^(d&7))+i][d].
// ---------------------------------------------------------------------------
__global__ __launch_bounds__(256) void ker_pre(const float* __restrict__ pts,
                                               const float* __restrict__ A) {
    const int dd = blockIdx.x;           // 0..255
    const int t  = threadIdx.x;          // 64-col chunk c = t
    const float a0 = A[dd], a1 = A[DH + dd], a2 = A[2*DH + dd];
    f16* rowc = &g_eAtS[(size_t)dd*NPTS + t*64];
    f16* rows = &g_eAtS[(size_t)(DH + dd)*NPTS + t*64];
    const int sx = dd & 7;
    #pragma unroll
    for (int s = 0; s < 8; ++s) {
        const int nb = t*64 + 8*(s ^ sx);
        f16x8 vc, vs;
        #pragma unroll
        for (int i = 0; i < 8; ++i) {
            const float* pr = pts + (size_t)(nb + i)*3;
            float sn, cs_; fsincos(pr[0]*a0 + pr[1]*a1 + pr[2]*a2, &sn, &cs_);
            vc[i] = (f16)cs_; vs[i] = (f16)sn;
        }
        *(f16x8*)(rowc + 8*s) = vc;
        *(f16x8*)(rows + 8*s) = vs;
    }
}

// ---------------------------------------------------------------------------
// GEMM1: T = eB^T eA. Block: M=128 (64 q x {cos,sin}), N=256 d, BK=64 n.
// Grid (64,2,4) = 1024 blocks. 512 thr, 8 waves (2M x 4N), wave-tile 64x64.
// A (eB) trig -> padded ds_write; B (eA^T) swizzled global_load_lds. [R10]
// ---------------------------------------------------------------------------
__global__ __launch_bounds__(512) void ker_T(const float* __restrict__ pts,
                                             const float* __restrict__ B) {
    const int q0 = blockIdx.x * 64;
    const int d0 = blockIdx.y * 256;
    const int ks = blockIdx.z;               // n range [ks*4096, +4096)
    const int t  = threadIdx.x;
    const int lane = t & 63, wid = t >> 6;
    const int wm = wid >> 2, wn = wid & 3;
    const int l7 = lane & 7;

    __shared__ f16 Al[128][LDT];   // rows 0..63 cos q, 64..127 sin q (padded)
    __shared__ f16 Bl[256][64];    // [d][n] swizzled (gload_lds dest)

    f32x4 acc[4][4];
    #pragma unroll
    for (int a = 0; a < 4; ++a)
        #pragma unroll
        for (int bq = 0; bq < 4; ++bq) acc[a][bq] = (f32x4){0.f,0.f,0.f,0.f};

    // A-trig: qq = t>>3 (0..63), 8 n per iter at nn0=(t&7)*8
    const int qq  = t >> 3;
    const int nn0 = (t & 7) * 8;
    const float b0 = B[q0+qq], b1 = B[PH+q0+qq], b2 = B[2*PH+q0+qq];
    // B gload: wave covers rows 32*wid..+31 in 4 gloads of 8 rows each
    const size_t bsrc0 = (size_t)(d0 + 32*wid + (lane >> 3))*NPTS + 8*l7;
    // frag coords
    const int mrow = wm*64 + (lane & 15);
    const int ncol = wn*64 + (lane & 15);

    for (int c = 0; c < 64; ++c) {
        const int nb = ks*4096 + c*64;
        __syncthreads();   // previous compute's LDS reads done
        // B stage first (HBM latency hides under trig)
        #pragma unroll
        for (int i = 0; i < 4; ++i)
            gload16(&g_eAtS[0] + bsrc0 + (size_t)(8*i)*NPTS + (size_t)nb,
                    &Bl[32*wid + 8*i][0]);
        {   // A stage: 8 consecutive pts rows = 24 contiguous floats
            const float* pb = pts + (size_t)(nb + nn0)*3;
            const float4 F0 = *(const float4*)(pb);
            const float4 F1 = *(const float4*)(pb + 4);
            const float4 F2 = *(const float4*)(pb + 8);
            const float4 F3 = *(const float4*)(pb + 12);
            const float4 F4 = *(const float4*)(pb + 16);
            const float4 F5 = *(const float4*)(pb + 20);
            const float xx[8] = {F0.x, F0.w, F1.z, F2.y, F3.x, F3.w, F4.z, F5.y};
            const float yy[8] = {F0.y, F1.x, F1.w, F2.z, F3.y, F4.x, F4.w, F5.z};
            const float zz[8] = {F0.z, F1.y, F2.x, F2.w, F3.z, F4.y, F5.x, F5.w};
            f16x8 vc, vs;
            #pragma unroll
            for (int u = 0; u < 8; ++u) {
                float sn, cc; fsincos(xx[u]*b0 + yy[u]*b1 + zz[u]*b2, &sn, &cc);
                vc[u] = (f16)cc; vs[u] = (f16)sn;
            }
            *(f16x8*)&Al[qq][nn0]      = vc;
            *(f16x8*)&Al[64 + qq][nn0] = vs;
        }
        __syncthreads();   // drains vmcnt+lgkmcnt (compiler-emitted)
        #pragma unroll
        for (int kk = 0; kk < 2; ++kk) {
            f16x8 af[4], bf[4];
            #pragma unroll
            for (int mf = 0; mf < 4; ++mf)
                af[mf] = *(const f16x8*)&Al[mrow + mf*16][32*kk + (lane >> 4)*8];
            #pragma unroll
            for (int nf = 0; nf < 4; ++nf)
                bf[nf] = *(const f16x8*)&Bl[ncol + nf*16][(((lane >> 4) + 4*kk) ^ l7)*8];
            #pragma unroll
            for (int mf = 0; mf < 4; ++mf)
                #pragma unroll
                for (int nf = 0; nf < 4; ++nf)
                    acc[mf][nf] = __builtin_amdgcn_mfma_f32_16x16x32_f16(
                        af[mf], bf[nf], acc[mf][nf], 0, 0, 0);
        }
    }
    // epilogue: wave wm: 0=cos rows, 1=sin rows; D row=(l>>4)*4+j, col=l&15
    #pragma unroll
    for (int mf = 0; mf < 4; ++mf) {
        const int qrow = q0 + mf*16 + (lane >> 4)*4;
        #pragma unroll
        for (int nf = 0; nf < 4; ++nf) {
            const int d = d0 + wn*64 + nf*16 + (lane & 15);
            f16x4 v;
            #pragma unroll
            for (int j = 0; j < 4; ++j) v[j] = (f16)acc[mf][nf][j];
            *(f16x4*)&g_Tt[ks][d][(size_t)wm*PH + qrow] = v;
        }
    }
}

// ---------------------------------------------------------------------------
// Sum 4 T partials -> g_TsS: interleaved [d][2q+cs], XOR-8 swizzled per
// 64-half chunk (physical slot s holds logical slot s^(d&7)).
// ---------------------------------------------------------------------------
__global__ __launch_bounds__(256) void ker_tsum() {
    const int u  = blockIdx.x*256 + threadIdx.x;   // 2048 blocks x 256 thr
    const int d  = u >> 10;                        // 0..511
    const int jj = u & 1023;
    const int c = jj >> 3, s = jj & 7;
    const int klb = 64*c + 8*(s ^ (d & 7));        // logical interleaved-k base
    const int q0_ = klb >> 1;                      // 4 q values
    float oc[4] = {0,0,0,0}, os[4] = {0,0,0,0};
    #pragma unroll
    for (int z = 0; z < 4; ++z) {
        const f16x4 a  = *(const f16x4*)&g_Tt[z][d][q0_];
        const f16x4 bs = *(const f16x4*)&g_Tt[z][d][PH + q0_];
        #pragma unroll
        for (int j = 0; j < 4; ++j) { oc[j] += (float)a[j]; os[j] += (float)bs[j]; }
    }
    f16x8 v;
    #pragma unroll
    for (int j = 0; j < 4; ++j) { v[2*j] = (f16)oc[j]; v[2*j+1] = (f16)os[j]; }
    *(f16x8*)&g_TsS[(size_t)d*(2*PH) + 64*c + 8*s] = v;
}

// ---------------------------------------------------------------------------
// GEMM2: G = eB T. Block: M=128 n, N=256 d, BK=64 interleaved k (=32 q x cs).
// Grid (128,2,2) = 512 blocks. 512 thr, 8 waves (2M x 4N), wave-tile 64x64.
// A (eB cos/sin interleaved) trig -> padded ds_write; B (g_TsS) swizzled
// global_load_lds -- removes ker_G's 2.1e7 bank-conflict cycles (8-way on
// the old [256][32] linear tiles).
// ---------------------------------------------------------------------------
__global__ __launch_bounds__(512) void ker_G(const float* __restrict__ pts,
                                             const float* __restrict__ B) {
    const int n0 = blockIdx.x * 128;
    const int d0 = blockIdx.y * 256;
    const int ks = blockIdx.z;               // ik range [ks*4096, +4096)
    const int t  = threadIdx.x;
    const int lane = t & 63, wid = t >> 6;
    const int wm = wid >> 2, wn = wid & 3;
    const int l7 = lane & 7;

    __shared__ f16 Al[128][LDT];   // [n][ik] padded
    __shared__ f16 Bl[256][64];    // [d][ik] swizzled (gload_lds dest)

    f32x4 acc[4][4];
    #pragma unroll
    for (int a = 0; a < 4; ++a)
        #pragma unroll
        for (int bq = 0; bq < 4; ++bq) acc[a][bq] = (f32x4){0.f,0.f,0.f,0.f};

    // A-trig: nn = t>>2 (0..127); ik chunk (t&3)*16 -> 8 q per thread per iter
    const int nn   = t >> 2;
    const int ikc  = (t & 3) * 16;
    const int qch8 = (t & 3) * 8;
    const float px = pts[(size_t)(n0+nn)*3];
    const float py = pts[(size_t)(n0+nn)*3 + 1];
    const float pz = pts[(size_t)(n0+nn)*3 + 2];
    // B gload: wave covers d-rows 32*wid..+31 in 4 gloads of 8 rows each
    const size_t bsrc0 = (size_t)(d0 + 32*wid + (lane >> 3))*(2*PH) + 8*l7;
    const int mrow = wm*64 + (lane & 15);
    const int ncol = wn*64 + (lane & 15);

    for (int c = 0; c < 64; ++c) {
        const int ikb = ks*4096 + c*64;      // interleaved-k base
        const int qb  = ikb >> 1;            // q base
        __syncthreads();
        // B stage first (HBM/L3 latency hides under trig)
        #pragma unroll
        for (int i = 0; i < 4; ++i)
            gload16(&g_TsS[0] + bsrc0 + (size_t)(8*i)*(2*PH) + (size_t)ikb,
                    &Bl[32*wid + 8*i][0]);
        {   // A stage: 8 betas -> 16 interleaved (cos,sin) halfs
            const int qg = qb + qch8;
            const float4 X0 = *(const float4*)&B[qg];
            const float4 X1 = *(const float4*)&B[qg + 4];
            const float4 Y0 = *(const float4*)&B[PH + qg];
            const float4 Y1 = *(const float4*)&B[PH + qg + 4];
            const float4 Z0 = *(const float4*)&B[2*PH + qg];
            const float4 Z1 = *(const float4*)&B[2*PH + qg + 4];
            const float bx[8] = {X0.x,X0.y,X0.z,X0.w, X1.x,X1.y,X1.z,X1.w};
            const float by[8] = {Y0.x,Y0.y,Y0.z,Y0.w, Y1.x,Y1.y,Y1.z,Y1.w};
            const float bz[8] = {Z0.x,Z0.y,Z0.z,Z0.w, Z1.x,Z1.y,Z1.z,Z1.w};
            f16x8 v0, v1;
            #pragma unroll
            for (int u = 0; u < 8; ++u) {
                float sn, cc; fsincos(px*bx[u] + py*by[u] + pz*bz[u], &sn, &cc);
                if (u < 4) { v0[2*u]   = (f16)cc; v0[2*u+1]     = (f16)sn; }
                else       { v1[2*(u-4)] = (f16)cc; v1[2*(u-4)+1] = (f16)sn; }
            }
            *(f16x8*)&Al[nn][ikc]     = v0;
            *(f16x8*)&Al[nn][ikc + 8] = v1;
        }
        __syncthreads();
        #pragma unroll
        for (int kk = 0; kk < 2; ++kk) {
            f16x8 af[4], bf[4];
            #pragma unroll
            for (int mf = 0; mf < 4; ++mf)
                af[mf] = *(const f16x8*)&Al[mrow + mf*16][32*kk + (lane >> 4)*8];
            #pragma unroll
            for (int nf = 0; nf < 4; ++nf)
                bf[nf] = *(const f16x8*)&Bl[ncol + nf*16][(((lane >> 4) + 4*kk) ^ l7)*8];
            #pragma unroll
            for (int mf = 0; mf < 4; ++mf)
                #pragma unroll
                for (int nf = 0; nf < 4; ++nf)
                    acc[mf][nf] = __builtin_amdgcn_mfma_f32_16x16x32_f16(
                        af[mf], bf[nf], acc[mf][nf], 0, 0, 0);
        }
    }
    // epilogue -> g_G[ks][n][d] fp32
    #pragma unroll
    for (int mf = 0; mf < 4; ++mf) {
        const int nbase = n0 + wm*64 + mf*16 + (lane >> 4)*4;
        #pragma unroll
        for (int nf = 0; nf < 4; ++nf) {
            const int d = d0 + wn*64 + nf*16 + (lane & 15);
            #pragma unroll
            for (int j = 0; j < 4; ++j)
                g_G[ks][nbase + j][d] = acc[mf][nf][j];
        }
    }
}

// ---------------------------------------------------------------------------
// Epilogue: Gc = (Gr+i*Gi)*conj(e^{i alpha}) (|e^{ia}|=1, divide==conj-mult;
// rotation preserves row norm -> scale = 16/||G row||). Output = REAL part.
// ---------------------------------------------------------------------------
__global__ __launch_bounds__(256) void ker_fin(const float* __restrict__ pts,
                                               const float* __restrict__ A,
                                               float* __restrict__ out) {
    const int n = blockIdx.x;
    const int k = threadIdx.x;  // 0..255
    const float p0 = pts[(size_t)n*3], p1 = pts[(size_t)n*3+1], p2 = pts[(size_t)n*3+2];
    const float alp = p0*A[k] + p1*A[DH + k] + p2*A[2*DH + k];
    float sa, ca; fsincos(alp, &sa, &ca);
    const float Gr = g_G[0][n][k]      + g_G[1][n][k];
    const float Gi = g_G[0][n][DH + k] + g_G[1][n][DH + k];
    const float Re = Gr*ca + Gi*sa;
    float nr = Gr*Gr + Gi*Gi;
    #pragma unroll
    for (int off = 32; off > 0; off >>= 1) nr += __shfl_down(nr, off, 64);
    __shared__ float wsum[4];
    if ((k & 63) == 0) wsum[k >> 6] = nr;
    __syncthreads();
    const float total = wsum[0] + wsum[1] + wsum[2] + wsum[3];
    const float scale = 16.0f * rsqrtf(total);
    out[(size_t)n*DH + k] = Re * scale;
}

extern "C" void kernel_launch(void* const* d_in, const int* in_sizes, int n_in,
                              void* d_out, int out_size, void* d_ws, size_t ws_size,
                              hipStream_t stream) {
    const float* pts = (const float*)d_in[0];
    const float* A   = (const float*)d_in[1];
    const float* B   = (const float*)d_in[2];
    float* out = (float*)d_out;
    (void)d_ws; (void)ws_size; (void)out_size;

    ker_pre <<<256, 256, 0, stream>>>(pts, A);
    ker_T   <<<dim3(64, 2, 4), 512, 0, stream>>>(pts, B);
    ker_tsum<<<2048, 256, 0, stream>>>();
    ker_G   <<<dim3(128, 2, 2), 512, 0, stream>>>(pts, B);
    ker_fin <<<16384, 256, 0, stream>>>(pts, A, out);
}

// Round 12
// 353.306 us; speedup vs baseline: 1.2101x; 1.0166x over previous
//
#include <hip/hip_runtime.h>

#define NPTS 16384
#define DH 256
#define PH 4096
#define D2 512

typedef _Float16 f16;
typedef _Float16 f16x4 __attribute__((ext_vector_type(4)));
typedef _Float16 f16x8 __attribute__((ext_vector_type(8)));
typedef float f32x4 __attribute__((ext_vector_type(4)));

// Static device scratch (d_out is only 16 MB = real part; d_ws size unknown).
// All buffers fully rewritten before use each call (deterministic).
// Swizzle convention (ALL LDS tiles + pre-swizzled globals): within each
// 64-half (128 B) row chunk, physical 16B slot s holds logical slot
// s^(row&7). R7 measured this layout at SQ_LDS_BANK_CONFLICT == 0.
__device__ f16   g_eAtS[(size_t)D2 * NPTS];   // 16 MB: eA^T fp16, swizzled
__device__ f16   g_Tt[4][D2][2*PH];           // 64 MB: T K-split partials [z][d][cs*PH+q]
__device__ f16   g_TsS[(size_t)D2 * 2*PH];    //  8 MB: T summed, [d][2q+cs] swizzled
__device__ float g_G[2][NPTS][D2];            // 64 MB: G K-split partials

__device__ __forceinline__ void gload16(const void* g, void* l) {
    __builtin_amdgcn_global_load_lds((const __attribute__((address_space(1))) void*)g,
                                     (__attribute__((address_space(3))) void*)l, 16, 0, 0);
}

__device__ __forceinline__ void fsincos(float x, float* s, float* c) {
    *s = __sinf(x); *c = __cosf(x);
}

// ---------------------------------------------------------------------------
// eA^T precompute, swizzled: g_eAtS[d][64c+8s+i] = eA[64c+8(s^(d&7))+i][d].
// ---------------------------------------------------------------------------
__global__ __launch_bounds__(256) void ker_pre(const float* __restrict__ pts,
                                               const float* __restrict__ A) {
    const int dd = blockIdx.x;           // 0..255
    const int t  = threadIdx.x;          // 64-col chunk c = t
    const float a0 = A[dd], a1 = A[DH + dd], a2 = A[2*DH + dd];
    f16* rowc = &g_eAtS[(size_t)dd*NPTS + t*64];
    f16* rows = &g_eAtS[(size_t)(DH + dd)*NPTS + t*64];
    const int sx = dd & 7;
    #pragma unroll
    for (int s = 0; s < 8; ++s) {
        const int nb = t*64 + 8*(s ^ sx);
        f16x8 vc, vs;
        #pragma unroll
        for (int i = 0; i < 8; ++i) {
            const float* pr = pts + (size_t)(nb + i)*3;
            float sn, cs_; fsincos(pr[0]*a0 + pr[1]*a1 + pr[2]*a2, &sn, &cs_);
            vc[i] = (f16)cs_; vs[i] = (f16)sn;
        }
        *(f16x8*)(rowc + 8*s) = vc;
        *(f16x8*)(rows + 8*s) = vs;
    }
}

// ---------------------------------------------------------------------------
// GEMM1: T = eB^T eA. Block: M=128 (64 q x {cos,sin}), N=256 d, BK=64 n.
// Grid (64,2,4) = 1024 blocks. 512 thr, 8 waves (2M x 4N), wave-tile 64x64.
// A (eB) trig -> XOR-swizzled ds_write [128][64] (R7: 0 conflicts; the
// R10/R11 pad-72 layout was an 8-way conflict on A-frag reads);
// B (eA^T) swizzled global_load_lds.
// ---------------------------------------------------------------------------
__global__ __launch_bounds__(512) void ker_T(const float* __restrict__ pts,
                                             const float* __restrict__ B) {
    const int q0 = blockIdx.x * 64;
    const int d0 = blockIdx.y * 256;
    const int ks = blockIdx.z;               // n range [ks*4096, +4096)
    const int t  = threadIdx.x;
    const int lane = t & 63, wid = t >> 6;
    const int wm = wid >> 2, wn = wid & 3;
    const int l7 = lane & 7;

    __shared__ f16 Al[128][64];    // rows 0..63 cos q, 64..127 sin q (XOR-swz)
    __shared__ f16 Bl[256][64];    // [d][n] swizzled (gload_lds dest)

    f32x4 acc[4][4];
    #pragma unroll
    for (int a = 0; a < 4; ++a)
        #pragma unroll
        for (int bq = 0; bq < 4; ++bq) acc[a][bq] = (f32x4){0.f,0.f,0.f,0.f};

    // A-trig: qq = t>>3 (0..63), 8 n per iter, logical slot t&7
    const int qq  = t >> 3;
    const int nn0 = (t & 7) * 8;
    const int wsl = ((t & 7) ^ (qq & 7)) * 8;   // physical slot offset (halfs)
    const float b0 = B[q0+qq], b1 = B[PH+q0+qq], b2 = B[2*PH+q0+qq];
    // B gload: wave covers rows 32*wid..+31 in 4 gloads of 8 rows each
    const size_t bsrc0 = (size_t)(d0 + 32*wid + (lane >> 3))*NPTS + 8*l7;
    // frag coords
    const int mrow = wm*64 + (lane & 15);
    const int ncol = wn*64 + (lane & 15);

    for (int c = 0; c < 64; ++c) {
        const int nb = ks*4096 + c*64;
        __syncthreads();   // previous compute's LDS reads done
        // B stage first (HBM latency hides under trig)
        #pragma unroll
        for (int i = 0; i < 4; ++i)
            gload16(&g_eAtS[0] + bsrc0 + (size_t)(8*i)*NPTS + (size_t)nb,
                    &Bl[32*wid + 8*i][0]);
        {   // A stage: 8 consecutive pts rows = 24 contiguous floats
            const float* pb = pts + (size_t)(nb + nn0)*3;
            const float4 F0 = *(const float4*)(pb);
            const float4 F1 = *(const float4*)(pb + 4);
            const float4 F2 = *(const float4*)(pb + 8);
            const float4 F3 = *(const float4*)(pb + 12);
            const float4 F4 = *(const float4*)(pb + 16);
            const float4 F5 = *(const float4*)(pb + 20);
            const float xx[8] = {F0.x, F0.w, F1.z, F2.y, F3.x, F3.w, F4.z, F5.y};
            const float yy[8] = {F0.y, F1.x, F1.w, F2.z, F3.y, F4.x, F4.w, F5.z};
            const float zz[8] = {F0.z, F1.y, F2.x, F2.w, F3.z, F4.y, F5.x, F5.w};
            f16x8 vc, vs;
            #pragma unroll
            for (int u = 0; u < 8; ++u) {
                float sn, cc; fsincos(xx[u]*b0 + yy[u]*b1 + zz[u]*b2, &sn, &cc);
                vc[u] = (f16)cc; vs[u] = (f16)sn;
            }
            *(f16x8*)&Al[qq][wsl]      = vc;   // (64+qq)&7 == qq&7
            *(f16x8*)&Al[64 + qq][wsl] = vs;
        }
        __syncthreads();   // drains vmcnt+lgkmcnt (compiler-emitted)
        #pragma unroll
        for (int kk = 0; kk < 2; ++kk) {
            f16x8 af[4], bf[4];
            #pragma unroll
            for (int mf = 0; mf < 4; ++mf)   // (mrow+mf*16)&7 == l7
                af[mf] = *(const f16x8*)&Al[mrow + mf*16][(((lane >> 4) + 4*kk) ^ l7)*8];
            #pragma unroll
            for (int nf = 0; nf < 4; ++nf)
                bf[nf] = *(const f16x8*)&Bl[ncol + nf*16][(((lane >> 4) + 4*kk) ^ l7)*8];
            #pragma unroll
            for (int mf = 0; mf < 4; ++mf)
                #pragma unroll
                for (int nf = 0; nf < 4; ++nf)
                    acc[mf][nf] = __builtin_amdgcn_mfma_f32_16x16x32_f16(
                        af[mf], bf[nf], acc[mf][nf], 0, 0, 0);
        }
    }
    // epilogue: wave wm: 0=cos rows, 1=sin rows; D row=(l>>4)*4+j, col=l&15
    #pragma unroll
    for (int mf = 0; mf < 4; ++mf) {
        const int qrow = q0 + mf*16 + (lane >> 4)*4;
        #pragma unroll
        for (int nf = 0; nf < 4; ++nf) {
            const int d = d0 + wn*64 + nf*16 + (lane & 15);
            f16x4 v;
            #pragma unroll
            for (int j = 0; j < 4; ++j) v[j] = (f16)acc[mf][nf][j];
            *(f16x4*)&g_Tt[ks][d][(size_t)wm*PH + qrow] = v;
        }
    }
}

// ---------------------------------------------------------------------------
// Sum 4 T partials -> g_TsS: interleaved [d][2q+cs], XOR-8 swizzled per
// 64-half chunk (physical slot s holds logical slot s^(d&7)).
// ---------------------------------------------------------------------------
__global__ __launch_bounds__(256) void ker_tsum() {
    const int u  = blockIdx.x*256 + threadIdx.x;   // 2048 blocks x 256 thr
    const int d  = u >> 10;                        // 0..511
    const int jj = u & 1023;
    const int c = jj >> 3, s = jj & 7;
    const int klb = 64*c + 8*(s ^ (d & 7));        // logical interleaved-k base
    const int q0_ = klb >> 1;                      // 4 q values
    float oc[4] = {0,0,0,0}, os[4] = {0,0,0,0};
    #pragma unroll
    for (int z = 0; z < 4; ++z) {
        const f16x4 a  = *(const f16x4*)&g_Tt[z][d][q0_];
        const f16x4 bs = *(const f16x4*)&g_Tt[z][d][PH + q0_];
        #pragma unroll
        for (int j = 0; j < 4; ++j) { oc[j] += (float)a[j]; os[j] += (float)bs[j]; }
    }
    f16x8 v;
    #pragma unroll
    for (int j = 0; j < 4; ++j) { v[2*j] = (f16)oc[j]; v[2*j+1] = (f16)os[j]; }
    *(f16x8*)&g_TsS[(size_t)d*(2*PH) + 64*c + 8*s] = v;
}

// ---------------------------------------------------------------------------
// GEMM2: G = eB T. Block: M=128 n, N=256 d, BK=64 interleaved k (=32 q x cs).
// Grid (128,2,2) = 512 blocks. 512 thr, 8 waves (2M x 4N), wave-tile 64x64.
// A (eB cos/sin interleaved) trig -> XOR-swizzled ds_write [128][64];
// B (g_TsS) swizzled global_load_lds.
// ---------------------------------------------------------------------------
__global__ __launch_bounds__(512) void ker_G(const float* __restrict__ pts,
                                             const float* __restrict__ B) {
    const int n0 = blockIdx.x * 128;
    const int d0 = blockIdx.y * 256;
    const int ks = blockIdx.z;               // ik range [ks*4096, +4096)
    const int t  = threadIdx.x;
    const int lane = t & 63, wid = t >> 6;
    const int wm = wid >> 2, wn = wid & 3;
    const int l7 = lane & 7;

    __shared__ f16 Al[128][64];    // [n][ik] XOR-swizzled
    __shared__ f16 Bl[256][64];    // [d][ik] swizzled (gload_lds dest)

    f32x4 acc[4][4];
    #pragma unroll
    for (int a = 0; a < 4; ++a)
        #pragma unroll
        for (int bq = 0; bq < 4; ++bq) acc[a][bq] = (f32x4){0.f,0.f,0.f,0.f};

    // A-trig: nn = t>>2 (0..127); logical slots 2*(t&3), 2*(t&3)+1
    const int nn   = t >> 2;
    const int qch8 = (t & 3) * 8;
    const int sl0  = 2*(t & 3);
    const int sx   = nn & 7;
    const float px = pts[(size_t)(n0+nn)*3];
    const float py = pts[(size_t)(n0+nn)*3 + 1];
    const float pz = pts[(size_t)(n0+nn)*3 + 2];
    // B gload: wave covers d-rows 32*wid..+31 in 4 gloads of 8 rows each
    const size_t bsrc0 = (size_t)(d0 + 32*wid + (lane >> 3))*(2*PH) + 8*l7;
    const int mrow = wm*64 + (lane & 15);
    const int ncol = wn*64 + (lane & 15);

    for (int c = 0; c < 64; ++c) {
        const int ikb = ks*4096 + c*64;      // interleaved-k base
        const int qb  = ikb >> 1;            // q base
        __syncthreads();
        // B stage first (HBM/L3 latency hides under trig)
        #pragma unroll
        for (int i = 0; i < 4; ++i)
            gload16(&g_TsS[0] + bsrc0 + (size_t)(8*i)*(2*PH) + (size_t)ikb,
                    &Bl[32*wid + 8*i][0]);
        {   // A stage: 8 betas -> 16 interleaved (cos,sin) halfs
            const int qg = qb + qch8;
            const float4 X0 = *(const float4*)&B[qg];
            const float4 X1 = *(const float4*)&B[qg + 4];
            const float4 Y0 = *(const float4*)&B[PH + qg];
            const float4 Y1 = *(const float4*)&B[PH + qg + 4];
            const float4 Z0 = *(const float4*)&B[2*PH + qg];
            const float4 Z1 = *(const float4*)&B[2*PH + qg + 4];
            const float bx[8] = {X0.x,X0.y,X0.z,X0.w, X1.x,X1.y,X1.z,X1.w};
            const float by[8] = {Y0.x,Y0.y,Y0.z,Y0.w, Y1.x,Y1.y,Y1.z,Y1.w};
            const float bz[8] = {Z0.x,Z0.y,Z0.z,Z0.w, Z1.x,Z1.y,Z1.z,Z1.w};
            f16x8 v0, v1;
            #pragma unroll
            for (int u = 0; u < 8; ++u) {
                float sn, cc; fsincos(px*bx[u] + py*by[u] + pz*bz[u], &sn, &cc);
                if (u < 4) { v0[2*u]     = (f16)cc; v0[2*u+1]     = (f16)sn; }
                else       { v1[2*(u-4)] = (f16)cc; v1[2*(u-4)+1] = (f16)sn; }
            }
            *(f16x8*)&Al[nn][((sl0    ) ^ sx)*8] = v0;
            *(f16x8*)&Al[nn][((sl0 + 1) ^ sx)*8] = v1;
        }
        __syncthreads();
        #pragma unroll
        for (int kk = 0; kk < 2; ++kk) {
            f16x8 af[4], bf[4];
            #pragma unroll
            for (int mf = 0; mf < 4; ++mf)   // (mrow+mf*16)&7 == l7
                af[mf] = *(const f16x8*)&Al[mrow + mf*16][(((lane >> 4) + 4*kk) ^ l7)*8];
            #pragma unroll
            for (int nf = 0; nf < 4; ++nf)
                bf[nf] = *(const f16x8*)&Bl[ncol + nf*16][(((lane >> 4) + 4*kk) ^ l7)*8];
            #pragma unroll
            for (int mf = 0; mf < 4; ++mf)
                #pragma unroll
                for (int nf = 0; nf < 4; ++nf)
                    acc[mf][nf] = __builtin_amdgcn_mfma_f32_16x16x32_f16(
                        af[mf], bf[nf], acc[mf][nf], 0, 0, 0);
        }
    }
    // epilogue -> g_G[ks][n][d] fp32
    #pragma unroll
    for (int mf = 0; mf < 4; ++mf) {
        const int nbase = n0 + wm*64 + mf*16 + (lane >> 4)*4;
        #pragma unroll
        for (int nf = 0; nf < 4; ++nf) {
            const int d = d0 + wn*64 + nf*16 + (lane & 15);
            #pragma unroll
            for (int j = 0; j < 4; ++j)
                g_G[ks][nbase + j][d] = acc[mf][nf][j];
        }
    }
}

// ---------------------------------------------------------------------------
// Epilogue: Gc = (Gr+i*Gi)*conj(e^{i alpha}) (|e^{ia}|=1, divide==conj-mult;
// rotation preserves row norm -> scale = 16/||G row||). Output = REAL part.
// ---------------------------------------------------------------------------
__global__ __launch_bounds__(256) void ker_fin(const float* __restrict__ pts,
                                               const float* __restrict__ A,
                                               float* __restrict__ out) {
    const int n = blockIdx.x;
    const int k = threadIdx.x;  // 0..255
    const float p0 = pts[(size_t)n*3], p1 = pts[(size_t)n*3+1], p2 = pts[(size_t)n*3+2];
    const float alp = p0*A[k] + p1*A[DH + k] + p2*A[2*DH + k];
    float sa, ca; fsincos(alp, &sa, &ca);
    const float Gr = g_G[0][n][k]      + g_G[1][n][k];
    const float Gi = g_G[0][n][DH + k] + g_G[1][n][DH + k];
    const float Re = Gr*ca + Gi*sa;
    float nr = Gr*Gr + Gi*Gi;
    #pragma unroll
    for (int off = 32; off > 0; off >>= 1) nr += __shfl_down(nr, off, 64);
    __shared__ float wsum[4];
    if ((k & 63) == 0) wsum[k >> 6] = nr;
    __syncthreads();
    const float total = wsum[0] + wsum[1] + wsum[2] + wsum[3];
    const float scale = 16.0f * rsqrtf(total);
    out[(size_t)n*DH + k] = Re * scale;
}

extern "C" void kernel_launch(void* const* d_in, const int* in_sizes, int n_in,
                              void* d_out, int out_size, void* d_ws, size_t ws_size,
                              hipStream_t stream) {
    const float* pts = (const float*)d_in[0];
    const float* A   = (const float*)d_in[1];
    const float* B   = (const float*)d_in[2];
    float* out = (float*)d_out;
    (void)d_ws; (void)ws_size; (void)out_size;

    ker_pre <<<256, 256, 0, stream>>>(pts, A);
    ker_T   <<<dim3(64, 2, 4), 512, 0, stream>>>(pts, B);
    ker_tsum<<<2048, 256, 0, stream>>>();
    ker_G   <<<dim3(128, 2, 2), 512, 0, stream>>>(pts, B);
    ker_fin <<<16384, 256, 0, stream>>>(pts, A, out);
}